// Round 5
// baseline (500.679 us; speedup 1.0000x reference)
//
#include <hip/hip_runtime.h>
#include <hip/hip_bf16.h>
#include <hip/hip_cooperative_groups.h>

namespace cg = cooperative_groups;

#define ENT_D 256
#define REL_D 256
#define HIST_D 512
#define ACT_DD 512
#define IN_DD 1024
#define BB 512
#define AA 256

typedef short bf16x8 __attribute__((ext_vector_type(8)));
typedef float floatx4 __attribute__((ext_vector_type(4)));

__device__ __forceinline__ unsigned short f2bf(float f) {
    unsigned u = __builtin_bit_cast(unsigned, f);
    return (unsigned short)((u + 0x7fffu + ((u >> 16) & 1u)) >> 16);  // RNE
}

// ---------------------------------------------------------------------------
// Single cooperative kernel; 512 blocks x 256 threads (2 blocks/CU resident).
// Phase 1: pack W1/W2/X into MFMA fragment-major bf16 layouts
// Phase 2: GEMM1  H = relu(X@W1+b1) -> A-pack bf16     (blocks 0..255)
// Phase 3: GEMM2  X2 = H@W2+b2 fp32 row-major          (blocks 256..511)
// Phase 4: score (mask-skip, 8-wide ILP gather) + softmax + entropy
// Layouts per 16x16x32 MFMA:
//  A-pack [m_tile][k_tile][lane][8]: A[mt*16+(lane&15)][kt*32+(lane>>4)*8+j]
//  B-pack [n_tile][k_tile][lane][8]: B[kt*32+(lane>>4)*8+j][nt*16+(lane&15)]
// ---------------------------------------------------------------------------
__global__ __launch_bounds__(256, 2) void fused_kernel(
    const int* __restrict__ cur, const int* __restrict__ qrel,
    const float* __restrict__ hist,
    const int* __restrict__ r_space, const int* __restrict__ e_space,
    const int* __restrict__ amask,
    const float* __restrict__ ent_emb, const float* __restrict__ rel_emb,
    const float* __restrict__ W1, const float* __restrict__ b1,
    const float* __restrict__ W2, const float* __restrict__ b2,
    unsigned short* __restrict__ W1p, unsigned short* __restrict__ W2p,
    unsigned short* __restrict__ Xp, unsigned short* __restrict__ Hp,
    float* __restrict__ X2,
    float* __restrict__ dist, float* __restrict__ ent_out)
{
    cg::grid_group grid = cg::this_grid();

    __shared__ unsigned short sH[1024];          // gemm1 repack (2 KB)
    __shared__ __align__(16) float x2s[ACT_DD];  // score (2 KB)
    __shared__ float sc[AA];
    __shared__ int   list[AA];
    __shared__ int   wcnt[4];
    __shared__ int   n_u_s;
    __shared__ float red[4];

    const int blk  = blockIdx.x;
    const int tid  = threadIdx.x;
    const int wave = tid >> 6, lane = tid & 63;
    const int l15  = lane & 15, quad = lane >> 4;

    // ================= Phase 1: pack (2560 tile-waves over 2048 slots) ====
    for (int wid = blk * 4 + wave; wid < 2560; wid += 2048) {
        unsigned short v[8];
        if (wid < 1024) {                      // W1 B-pack
            const int t = wid, nt = t >> 5, kt = t & 31;
            const int n = nt * 16 + l15, k0 = kt * 32 + quad * 8;
#pragma unroll
            for (int j = 0; j < 8; ++j) v[j] = f2bf(W1[(size_t)(k0 + j) * ACT_DD + n]);
            *(bf16x8*)(W1p + ((size_t)t * 64 + lane) * 8) = *(bf16x8*)v;
        } else if (wid < 1536) {               // W2 B-pack
            const int t = wid - 1024, nt = t >> 4, kt = t & 15;
            const int n = nt * 16 + l15, k0 = kt * 32 + quad * 8;
#pragma unroll
            for (int j = 0; j < 8; ++j) v[j] = f2bf(W2[(size_t)(k0 + j) * ACT_DD + n]);
            *(bf16x8*)(W2p + ((size_t)t * 64 + lane) * 8) = *(bf16x8*)v;
        } else {                               // X = [E(cur)|hist|R(qrel)] A-pack
            const int t = wid - 1536, mt = t >> 5, kt = t & 31;
            const int m = mt * 16 + l15, k0 = kt * 32 + quad * 8;
            const float* src;
            if (k0 < ENT_D)               src = ent_emb + (size_t)cur[m] * ENT_D + k0;
            else if (k0 < ENT_D + HIST_D) src = hist + (size_t)m * HIST_D + (k0 - ENT_D);
            else                          src = rel_emb + (size_t)qrel[m] * REL_D + (k0 - ENT_D - HIST_D);
            float4 a = *(const float4*)src, b = *(const float4*)(src + 4);
            v[0]=f2bf(a.x); v[1]=f2bf(a.y); v[2]=f2bf(a.z); v[3]=f2bf(a.w);
            v[4]=f2bf(b.x); v[5]=f2bf(b.y); v[6]=f2bf(b.z); v[7]=f2bf(b.w);
            *(bf16x8*)(Xp + ((size_t)t * 64 + lane) * 8) = *(bf16x8*)v;
        }
    }
    __threadfence();
    grid.sync();

    // ================= Phase 2: GEMM1 (blocks 0..255) =====================
    if (blk < 256) {
        const int mt = blk >> 3, by = blk & 7;
        const int nt = by * 4 + wave;
        const bf16x8* Av = (const bf16x8*)Xp  + (size_t)mt * 32 * 64 + lane;
        const bf16x8* Bv = (const bf16x8*)W1p + (size_t)nt * 32 * 64 + lane;
        floatx4 acc = {0.f, 0.f, 0.f, 0.f};
#pragma unroll 8
        for (int kt = 0; kt < 32; ++kt)
            acc = __builtin_amdgcn_mfma_f32_16x16x32_bf16(Av[kt * 64], Bv[kt * 64], acc, 0, 0, 0);

        const int col = nt * 16 + l15;
        const float bj = b1[col];
        const int n_loc = wave * 16 + l15;
        const int tile_loc = n_loc >> 5, quad2 = (n_loc & 31) >> 3, j2 = n_loc & 7;
#pragma unroll
        for (int reg = 0; reg < 4; ++reg) {
            const int row = quad * 4 + reg;
            const float h = fmaxf(acc[reg] + bj, 0.f);
            sH[tile_loc * 512 + (row + 16 * quad2) * 8 + j2] = f2bf(h);
        }
        __syncthreads();
        const int h = tid * 4;
        const int tl = h >> 9, rest = h & 511;
        const size_t dst = ((size_t)(mt * 16 + by * 2 + tl) * 512 + rest);
        *(uint2*)(Hp + dst) = *(const uint2*)(sH + h);
    }
    __threadfence();
    grid.sync();

    // ================= Phase 3: GEMM2 (blocks 256..511) ===================
    if (blk >= 256) {
        const int bb = blk - 256;
        const int mt = bb >> 3, by = bb & 7;
        const int nt = by * 4 + wave;
        const bf16x8* Av = (const bf16x8*)Hp  + (size_t)mt * 16 * 64 + lane;
        const bf16x8* Bv = (const bf16x8*)W2p + (size_t)nt * 16 * 64 + lane;
        floatx4 acc = {0.f, 0.f, 0.f, 0.f};
#pragma unroll
        for (int kt = 0; kt < 16; ++kt)
            acc = __builtin_amdgcn_mfma_f32_16x16x32_bf16(Av[kt * 64], Bv[kt * 64], acc, 0, 0, 0);

        const int col = nt * 16 + l15;
        const float bj = b2[col];
#pragma unroll
        for (int reg = 0; reg < 4; ++reg) {
            const int m = mt * 16 + quad * 4 + reg;
            X2[(size_t)m * ACT_DD + col] = acc[reg] + bj;
        }
    }
    __threadfence();
    grid.sync();

    // ================= Phase 4: score + softmax + entropy =================
    // One row per block. Masked actions contribute exactly p=0 / 0 entropy
    // in the reference (exp(-1e31 - mx) == 0.0f) -> skip their gathers.
    const int b = blk;

    x2s[tid]       = X2[(size_t)b * ACT_DD + tid];
    x2s[tid + 256] = X2[(size_t)b * ACT_DD + tid + 256];

    const int m = amask[b * AA + tid];
    sc[tid] = 0.0f;
    const unsigned long long bal = __ballot(m != 0);
    const int pre = __popcll(bal & ((1ull << lane) - 1ull));
    if (lane == 0) wcnt[wave] = __popcll(bal);
    __syncthreads();

    {
        int off = 0;
#pragma unroll
        for (int w = 0; w < 4; ++w) if (w < wave) off += wcnt[w];
        if (m != 0) list[off + pre] = tid;
        if (tid == 0) n_u_s = wcnt[0] + wcnt[1] + wcnt[2] + wcnt[3];
    }
    __syncthreads();

    const int n_u = n_u_s;
    const int padded = (n_u + 31) & ~31;       // pass granularity 4 waves x 8
    if (tid < padded - n_u) list[n_u + tid] = list[0];
    __syncthreads();

    const float4 xr = ((const float4*)&x2s[0])[lane];       // rel half
    const float4 xe = ((const float4*)&x2s[REL_D])[lane];   // ent half

    for (int base = wave * 8; base < padded; base += 32) {
        int ai[8], ir[8], ie[8];
#pragma unroll
        for (int i = 0; i < 8; ++i) ai[i] = list[base + i];
#pragma unroll
        for (int i = 0; i < 8; ++i) {
            ir[i] = r_space[b * AA + ai[i]];
            ie[i] = e_space[b * AA + ai[i]];
        }
        float4 r4[8], e4[8];
#pragma unroll
        for (int i = 0; i < 8; ++i)
            r4[i] = ((const float4*)(rel_emb + (size_t)ir[i] * REL_D))[lane];
#pragma unroll
        for (int i = 0; i < 8; ++i)
            e4[i] = ((const float4*)(ent_emb + (size_t)ie[i] * ENT_D))[lane];

        float p[8];
#pragma unroll
        for (int i = 0; i < 8; ++i)
            p[i] = r4[i].x * xr.x + r4[i].y * xr.y + r4[i].z * xr.z + r4[i].w * xr.w
                 + e4[i].x * xe.x + e4[i].y * xe.y + e4[i].z * xe.z + e4[i].w * xe.w;
#pragma unroll
        for (int off = 32; off > 0; off >>= 1) {
#pragma unroll
            for (int i = 0; i < 8; ++i) p[i] += __shfl_xor(p[i], off, 64);
        }
        if (lane == 0) {
#pragma unroll
            for (int i = 0; i < 8; ++i) sc[ai[i]] = p[i];
        }
    }
    __syncthreads();

    const float s = (m != 0) ? sc[tid] : (sc[tid] - 1e31f);
    float v = s;
#pragma unroll
    for (int off = 32; off > 0; off >>= 1) v = fmaxf(v, __shfl_xor(v, off, 64));
    if (lane == 0) red[wave] = v;
    __syncthreads();
    const float mx = fmaxf(fmaxf(red[0], red[1]), fmaxf(red[2], red[3]));
    __syncthreads();

    const float e = __expf(s - mx);
    v = e;
#pragma unroll
    for (int off = 32; off > 0; off >>= 1) v += __shfl_xor(v, off, 64);
    if (lane == 0) red[wave] = v;
    __syncthreads();
    const float sum = red[0] + red[1] + red[2] + red[3];
    __syncthreads();

    const float p = e / sum;
    dist[(size_t)b * AA + tid] = p;

    v = p * __logf(p + 1e-20f);
#pragma unroll
    for (int off = 32; off > 0; off >>= 1) v += __shfl_xor(v, off, 64);
    if (lane == 0) red[wave] = v;
    __syncthreads();
    if (tid == 0) ent_out[b] = -(red[0] + red[1] + red[2] + red[3]);
}

extern "C" void kernel_launch(void* const* d_in, const int* in_sizes, int n_in,
                              void* d_out, int out_size, void* d_ws, size_t ws_size,
                              hipStream_t stream) {
    const int*   cur      = (const int*)d_in[0];
    const int*   qrel     = (const int*)d_in[1];
    const float* hist     = (const float*)d_in[2];
    const int*   r_space  = (const int*)d_in[3];
    const int*   e_space  = (const int*)d_in[4];
    const int*   amask    = (const int*)d_in[5];
    const float* ent_emb  = (const float*)d_in[6];
    const float* rel_emb  = (const float*)d_in[7];
    const float* W1       = (const float*)d_in[8];
    const float* b1       = (const float*)d_in[9];
    const float* W2       = (const float*)d_in[10];
    const float* b2       = (const float*)d_in[11];

    float* dist    = (float*)d_out;
    float* entropy = dist + (size_t)BB * AA;

    // ws layout: W1p 1M | W2p 0.5M | Xp 1M | Hp 0.5M | X2 1M
    char* w = (char*)d_ws;
    unsigned short* W1p = (unsigned short*)(w);
    unsigned short* W2p = (unsigned short*)(w + (1u << 20));
    unsigned short* Xp  = (unsigned short*)(w + (3u << 19));
    unsigned short* Hp  = (unsigned short*)(w + (5u << 19));
    float*          X2  = (float*)(w + (6u << 19));

    void* args[] = {
        (void*)&cur, (void*)&qrel, (void*)&hist,
        (void*)&r_space, (void*)&e_space, (void*)&amask,
        (void*)&ent_emb, (void*)&rel_emb,
        (void*)&W1, (void*)&b1, (void*)&W2, (void*)&b2,
        (void*)&W1p, (void*)&W2p, (void*)&Xp, (void*)&Hp, (void*)&X2,
        (void*)&dist, (void*)&entropy,
    };
    hipLaunchCooperativeKernel((void*)fused_kernel, dim3(512), dim3(256),
                               args, 0, stream);
}

// Round 6
// 178.755 us; speedup vs baseline: 2.8009x; 2.8009x over previous
//
#include <hip/hip_runtime.h>
#include <hip/hip_bf16.h>

#define ENT_D 256
#define REL_D 256
#define HIST_D 512
#define ACT_DD 512
#define IN_DD 1024
#define BB 512
#define AA 256

typedef short bf16x8 __attribute__((ext_vector_type(8)));
typedef float floatx4 __attribute__((ext_vector_type(4)));

__device__ __forceinline__ unsigned short f2bf(float f) {
    unsigned u = __builtin_bit_cast(unsigned, f);
    return (unsigned short)((u + 0x7fffu + ((u >> 16) & 1u)) >> 16);  // RNE
}

// ---------------------------------------------------------------------------
// Fragment-major pack layouts (per 16x16x32 MFMA):
//  A-pack  [m_tile][k_tile][lane][8]:  val = A[m_tile*16 + (lane&15)][k_tile*32 + (lane>>4)*8 + j]
//  B-pack  [n_tile][k_tile][lane][8]:  val = B[k_tile*32 + (lane>>4)*8 + j][n_tile*16 + (lane&15)]
// ---------------------------------------------------------------------------

__global__ __launch_bounds__(256) void pack_kernel(
    const int* __restrict__ cur, const int* __restrict__ qrel,
    const float* __restrict__ hist,
    const float* __restrict__ ent_emb, const float* __restrict__ rel_emb,
    const float* __restrict__ W1, const float* __restrict__ W2,
    unsigned short* __restrict__ W1p, unsigned short* __restrict__ W2p,
    unsigned short* __restrict__ Xp)
{
    const int wid  = blockIdx.x * 4 + (threadIdx.x >> 6);
    const int lane = threadIdx.x & 63;
    const int l15  = lane & 15;
    const int quad = lane >> 4;
    unsigned short v[8];

    if (wid < 1024) {                      // W1: B-pack, K=1024, N=512
        const int t = wid, nt = t >> 5, kt = t & 31;
        const int n = nt * 16 + l15, k0 = kt * 32 + quad * 8;
#pragma unroll
        for (int j = 0; j < 8; ++j) v[j] = f2bf(W1[(size_t)(k0 + j) * ACT_DD + n]);
        *(bf16x8*)(W1p + ((size_t)t * 64 + lane) * 8) = *(bf16x8*)v;
    } else if (wid < 1536) {               // W2: B-pack, K=512, N=512
        const int t = wid - 1024, nt = t >> 4, kt = t & 15;
        const int n = nt * 16 + l15, k0 = kt * 32 + quad * 8;
#pragma unroll
        for (int j = 0; j < 8; ++j) v[j] = f2bf(W2[(size_t)(k0 + j) * ACT_DD + n]);
        *(bf16x8*)(W2p + ((size_t)t * 64 + lane) * 8) = *(bf16x8*)v;
    } else {                               // X = [E(cur)|hist|R(qrel)]: A-pack, M=512, K=1024
        const int t = wid - 1536, mt = t >> 5, kt = t & 31;
        const int m = mt * 16 + l15, k0 = kt * 32 + quad * 8;
        const float* src;
        if (k0 < ENT_D)            src = ent_emb + (size_t)cur[m] * ENT_D + k0;
        else if (k0 < ENT_D + HIST_D) src = hist + (size_t)m * HIST_D + (k0 - ENT_D);
        else                       src = rel_emb + (size_t)qrel[m] * REL_D + (k0 - ENT_D - HIST_D);
        float4 a = *(const float4*)src, b = *(const float4*)(src + 4);
        v[0]=f2bf(a.x); v[1]=f2bf(a.y); v[2]=f2bf(a.z); v[3]=f2bf(a.w);
        v[4]=f2bf(b.x); v[5]=f2bf(b.y); v[6]=f2bf(b.z); v[7]=f2bf(b.w);
        *(bf16x8*)(Xp + ((size_t)t * 64 + lane) * 8) = *(bf16x8*)v;
    }
}

// GEMM1: H = relu(X@W1 + b1) -> Hp in A-pack layout (bf16), via LDS repack.
__global__ __launch_bounds__(256) void gemm1_kernel(
    const unsigned short* __restrict__ Xp, const unsigned short* __restrict__ W1p,
    const float* __restrict__ b1, unsigned short* __restrict__ Hp)
{
    __shared__ unsigned short sH[1024];
    const int mt = blockIdx.x, wave = threadIdx.x >> 6, lane = threadIdx.x & 63;
    const int nt = blockIdx.y * 4 + wave;

    const bf16x8* Av = (const bf16x8*)Xp  + (size_t)mt * 32 * 64 + lane;
    const bf16x8* Bv = (const bf16x8*)W1p + (size_t)nt * 32 * 64 + lane;
    floatx4 acc = {0.f, 0.f, 0.f, 0.f};
#pragma unroll 8
    for (int kt = 0; kt < 32; ++kt)
        acc = __builtin_amdgcn_mfma_f32_16x16x32_bf16(Av[kt * 64], Bv[kt * 64], acc, 0, 0, 0);

    const int col  = nt * 16 + (lane & 15);
    const float bj = b1[col];
    const int n_loc = wave * 16 + (lane & 15);
    const int tile_loc = n_loc >> 5, quad2 = (n_loc & 31) >> 3, j2 = n_loc & 7;
#pragma unroll
    for (int reg = 0; reg < 4; ++reg) {
        const int row = (lane >> 4) * 4 + reg;
        const float h = fmaxf(acc[reg] + bj, 0.f);
        sH[tile_loc * 512 + (row + 16 * quad2) * 8 + j2] = f2bf(h);
    }
    __syncthreads();
    const int h = threadIdx.x * 4;
    const int tl = h >> 9, rest = h & 511;
    const size_t dst = ((size_t)(mt * 16 + blockIdx.y * 2 + tl) * 512 + rest);
    *(uint2*)(Hp + dst) = *(const uint2*)(sH + h);
}

// GEMM2: X2 = H@W2 + b2 (fp32 out, row-major).
__global__ __launch_bounds__(256) void gemm2_kernel(
    const unsigned short* __restrict__ Hp, const unsigned short* __restrict__ W2p,
    const float* __restrict__ b2, float* __restrict__ X2)
{
    const int mt = blockIdx.x, wave = threadIdx.x >> 6, lane = threadIdx.x & 63;
    const int nt = blockIdx.y * 4 + wave;

    const bf16x8* Av = (const bf16x8*)Hp  + (size_t)mt * 16 * 64 + lane;
    const bf16x8* Bv = (const bf16x8*)W2p + (size_t)nt * 16 * 64 + lane;
    floatx4 acc = {0.f, 0.f, 0.f, 0.f};
#pragma unroll
    for (int kt = 0; kt < 16; ++kt)
        acc = __builtin_amdgcn_mfma_f32_16x16x32_bf16(Av[kt * 64], Bv[kt * 64], acc, 0, 0, 0);

    const int col = nt * 16 + (lane & 15);
    const float bj = b2[col];
#pragma unroll
    for (int reg = 0; reg < 4; ++reg) {
        const int m = mt * 16 + (lane >> 4) * 4 + reg;
        X2[(size_t)m * ACT_DD + col] = acc[reg] + bj;
    }
}

// Fused scores + softmax + entropy with MASK-SKIP.
// One block per batch row; 512 threads = 8 waves.
// sched_barrier(0) between the gather-load batch and the FMA batch forces all
// 16 global_load_dwordx4 to issue before first use (true 16-deep MLP per wave;
// without it the scheduler sinks loads into uses and holds only ~60 VGPRs).
__global__ __launch_bounds__(512) void score_softmax_kernel(
    const float* __restrict__ X2,
    const int* __restrict__ r_space, const int* __restrict__ e_space,
    const int* __restrict__ amask,
    const float* __restrict__ ent_emb, const float* __restrict__ rel_emb,
    float* __restrict__ dist, float* __restrict__ ent_out)
{
    __shared__ __align__(16) float x2s[ACT_DD];
    __shared__ float sc[AA];
    __shared__ int   list[AA];
    __shared__ int   wcnt[4];
    __shared__ int   n_u_s;
    __shared__ float red[8];

    const int b = blockIdx.x, tid = threadIdx.x;
    const int wave = tid >> 6, lane = tid & 63;

    x2s[tid] = X2[(size_t)b * ACT_DD + tid];

    // ---- compaction of unmasked action ids (waves 0-3 carry tid<256) ----
    int m = 0;
    unsigned long long bal = 0;
    int pre = 0;
    if (tid < AA) {
        m = amask[b * AA + tid];
        sc[tid] = 0.0f;
    }
    if (wave < 4) {
        bal = __ballot(m != 0);
        pre = __popcll(bal & ((1ull << lane) - 1ull));
        if (lane == 0) wcnt[wave] = __popcll(bal);
    }
    __syncthreads();

    if (wave < 4) {
        int off = 0;
#pragma unroll
        for (int w = 0; w < 4; ++w) if (w < wave) off += wcnt[w];
        if (m != 0) list[off + pre] = tid;
        if (tid == 0) n_u_s = wcnt[0] + wcnt[1] + wcnt[2] + wcnt[3];
    }
    __syncthreads();

    const int n_u = n_u_s;
    const int padded = (n_u + 63) & ~63;
    if (tid < padded - n_u) list[n_u + tid] = list[0];
    __syncthreads();

    const float4 xr = ((const float4*)&x2s[0])[lane];       // rel half
    const float4 xe = ((const float4*)&x2s[REL_D])[lane];   // ent half

    for (int base = wave * 8; base < padded; base += 64) {
        int ai[8], ir[8], ie[8];
#pragma unroll
        for (int i = 0; i < 8; ++i) ai[i] = list[base + i];
#pragma unroll
        for (int i = 0; i < 8; ++i) {
            ir[i] = r_space[b * AA + ai[i]];
            ie[i] = e_space[b * AA + ai[i]];
        }
        float4 r4[8], e4[8];
#pragma unroll
        for (int i = 0; i < 8; ++i)
            r4[i] = ((const float4*)(rel_emb + (size_t)ir[i] * REL_D))[lane];
#pragma unroll
        for (int i = 0; i < 8; ++i)
            e4[i] = ((const float4*)(ent_emb + (size_t)ie[i] * ENT_D))[lane];

        __builtin_amdgcn_sched_barrier(0);   // keep all 16 loads ahead of FMAs

        float p[8];
#pragma unroll
        for (int i = 0; i < 8; ++i)
            p[i] = r4[i].x * xr.x + r4[i].y * xr.y + r4[i].z * xr.z + r4[i].w * xr.w
                 + e4[i].x * xe.x + e4[i].y * xe.y + e4[i].z * xe.z + e4[i].w * xe.w;
#pragma unroll
        for (int off = 32; off > 0; off >>= 1) {
#pragma unroll
            for (int i = 0; i < 8; ++i) p[i] += __shfl_xor(p[i], off, 64);
        }
        if (lane == 0) {
#pragma unroll
            for (int i = 0; i < 8; ++i) sc[ai[i]] = p[i];
        }
    }
    __syncthreads();

    // ---- softmax + entropy over 256 scores ----
    float s = -3.0e38f;
    if (tid < AA) s = (m != 0) ? sc[tid] : (sc[tid] - 1e31f);  // sc=0 for masked
    float v = s;
#pragma unroll
    for (int off = 32; off > 0; off >>= 1) v = fmaxf(v, __shfl_xor(v, off, 64));
    if (lane == 0) red[wave] = v;
    __syncthreads();
    float mx = red[0];
#pragma unroll
    for (int w = 1; w < 8; ++w) mx = fmaxf(mx, red[w]);
    __syncthreads();

    const float e = (tid < AA) ? __expf(s - mx) : 0.0f;
    v = e;
#pragma unroll
    for (int off = 32; off > 0; off >>= 1) v += __shfl_xor(v, off, 64);
    if (lane == 0) red[wave] = v;
    __syncthreads();
    float sum = red[0];
#pragma unroll
    for (int w = 1; w < 8; ++w) sum += red[w];
    __syncthreads();

    const float p = e / sum;
    if (tid < AA) dist[(size_t)b * AA + tid] = p;

    v = (tid < AA) ? p * __logf(p + 1e-20f) : 0.0f;
#pragma unroll
    for (int off = 32; off > 0; off >>= 1) v += __shfl_xor(v, off, 64);
    if (lane == 0) red[wave] = v;
    __syncthreads();
    if (tid == 0) {
        float t = red[0];
#pragma unroll
        for (int w = 1; w < 8; ++w) t += red[w];
        ent_out[b] = -t;
    }
}

extern "C" void kernel_launch(void* const* d_in, const int* in_sizes, int n_in,
                              void* d_out, int out_size, void* d_ws, size_t ws_size,
                              hipStream_t stream) {
    const int*   cur      = (const int*)d_in[0];
    const int*   qrel     = (const int*)d_in[1];
    const float* hist     = (const float*)d_in[2];
    const int*   r_space  = (const int*)d_in[3];
    const int*   e_space  = (const int*)d_in[4];
    const int*   amask    = (const int*)d_in[5];
    const float* ent_emb  = (const float*)d_in[6];
    const float* rel_emb  = (const float*)d_in[7];
    const float* W1       = (const float*)d_in[8];
    const float* b1       = (const float*)d_in[9];
    const float* W2       = (const float*)d_in[10];
    const float* b2       = (const float*)d_in[11];

    float* dist    = (float*)d_out;
    float* entropy = dist + (size_t)BB * AA;

    // ws layout: W1p 1M | W2p 0.5M | Xp 1M | Hp 0.5M | X2 1M
    char* w = (char*)d_ws;
    unsigned short* W1p = (unsigned short*)(w);
    unsigned short* W2p = (unsigned short*)(w + (1u << 20));
    unsigned short* Xp  = (unsigned short*)(w + (3u << 19));
    unsigned short* Hp  = (unsigned short*)(w + (5u << 19));
    float*          X2  = (float*)(w + (6u << 19));

    pack_kernel<<<640, 256, 0, stream>>>(cur, qrel, hist, ent_emb, rel_emb, W1, W2, W1p, W2p, Xp);
    gemm1_kernel<<<dim3(32, 8), 256, 0, stream>>>(Xp, W1p, b1, Hp);
    gemm2_kernel<<<dim3(32, 8), 256, 0, stream>>>(Hp, W2p, b2, X2);
    score_softmax_kernel<<<512, 512, 0, stream>>>(X2, r_space, e_space, amask,
                                                  ent_emb, rel_emb, dist, entropy);
}